// Round 2
// baseline (141.185 us; speedup 1.0000x reference)
//
#include <hip/hip_runtime.h>
#include <hip/hip_bf16.h>
#include <cstdint>

#define N_IDE 4096
#define M_U   16384
#define D_DIM 256
#define EPSF  1e-12f
#define INV_M (1.0f / 16384.0f)

typedef _Float16 f16x8 __attribute__((ext_vector_type(8)));
typedef float    f32x4 __attribute__((ext_vector_type(4)));

// ---- async global->LDS 16B copy. LDS dest = wave-uniform base + lane*16. ----
__device__ __forceinline__ void gll16(const void* g, void* l) {
  __builtin_amdgcn_global_load_lds(
      (const __attribute__((address_space(1))) void*)(uintptr_t)g,
      (__attribute__((address_space(3))) void*)(uint32_t)(uintptr_t)l,
      16, 0, 0);
}

__device__ __forceinline__ unsigned short f2h_bits(float f) {
  _Float16 h = (_Float16)f;
  return __builtin_bit_cast(unsigned short, h);
}

// ---- Kernel 1: fp32 -> f16 convert + row squared-norms (one wave per row) ----
__global__ __launch_bounds__(256) void k_conv(const float* __restrict__ ide,
                                              const float* __restrict__ u,
                                              unsigned short* __restrict__ Ah,
                                              unsigned short* __restrict__ Bh,
                                              float* __restrict__ x2,
                                              float* __restrict__ y2) {
  int gw = (blockIdx.x * 256 + threadIdx.x) >> 6;
  int l  = threadIdx.x & 63;
  const float4* src;
  ushort4* dst;
  float* nrm;
  if (gw < N_IDE) {
    src = (const float4*)(ide + (size_t)gw * D_DIM);
    dst = (ushort4*)(Ah + (size_t)gw * D_DIM);
    nrm = x2 + gw;
  } else {
    int r = gw - N_IDE;
    src = (const float4*)(u + (size_t)r * D_DIM);
    dst = (ushort4*)(Bh + (size_t)r * D_DIM);
    nrm = y2 + r;
  }
  float4 v = src[l];
  float s = v.x * v.x + v.y * v.y + v.z * v.z + v.w * v.w;
  ushort4 o;
  o.x = f2h_bits(v.x); o.y = f2h_bits(v.y);
  o.z = f2h_bits(v.z); o.w = f2h_bits(v.w);
  dst[l] = o;
#pragma unroll
  for (int m = 1; m <= 32; m <<= 1) s += __shfl_xor(s, m, 64);
  if (l == 0) *nrm = s;
}

// ---- Kernel 2: barrier-free MFMA GEMM ----
// grid (32, 32), 512 threads (8 waves). Block tile 128 rows x 512 cols.
// A (128x256 f16, full K) staged ONCE into LDS (XOR-swizzled), one barrier.
// B is NOT staged: each wave loads its B fragments straight from L2 into
// registers (64B-granule coalesced; per-bx B slice is L2-resident since all
// same-bx blocks land on one XCD: linear_id % 8 has bx-period 32).
// Wave w owns cols [bx*512 + w*64, +64), all 128 rows: acc[8][4] (128 AGPR).
// Fully-unrolled K loop (8 steps x 32 MFMA), 1-step B register prefetch,
// ZERO barriers in the main loop -> no lockstep stalls, no vmcnt drains.
__global__ __launch_bounds__(512, 2) void k_gemm(const unsigned short* __restrict__ Ah,
                                                 const unsigned short* __restrict__ Bh,
                                                 const float* __restrict__ x2,
                                                 const float* __restrict__ y2,
                                                 float* __restrict__ partial) {
  __shared__ __align__(16) unsigned short sA[128 * 256];   // 64 KB
  __shared__ float rowacc[8][128];                         // 4 KB

  const int t    = threadIdx.x;
  const int w    = t >> 6;
  const int l    = t & 63;
  const int lrow = l & 15;
  const int lhi  = l >> 4;
  const int bx   = blockIdx.x;           // 0..31  (512 cols each)
  const int by   = blockIdx.y;           // 0..31  (128 rows each)

  // ---- stage A (128 rows x 256 K), XOR-swizzled in 16B chunks ----
#pragma unroll
  for (int i = 0; i < 8; ++i) {
    int L = i * 512 + t;                 // chunk id 0..4095
    int row = L >> 5;
    int p = L & 31;
    int c = (p & 24) | ((p & 7) ^ (row & 7));
    gll16(Ah + (size_t)(by * 128 + row) * D_DIM + c * 8,
          sA + (size_t)(i * 512 + w * 64) * 8);
  }
  __syncthreads();                       // the ONLY pre-epilogue barrier

  const int colbase = bx * 512 + w * 64;

  // per-lane B pointers: col = colbase + nj*16 + lrow, k-chunk base lhi*8;
  // per-step k advance is a compile-time offset (kt*64 bytes) after unroll.
  const unsigned short* bptr[4];
#pragma unroll
  for (int nj = 0; nj < 4; ++nj)
    bptr[nj] = Bh + (size_t)(colbase + nj * 16 + lrow) * D_DIM + lhi * 8;

  f32x4 acc[8][4];
#pragma unroll
  for (int mi = 0; mi < 8; ++mi)
#pragma unroll
    for (int nj = 0; nj < 4; ++nj)
      acc[mi][nj] = (f32x4){0.f, 0.f, 0.f, 0.f};

  f16x8 bfb[2][4];
#pragma unroll
  for (int nj = 0; nj < 4; ++nj) bfb[0][nj] = *(const f16x8*)(bptr[nj]);

#pragma unroll
  for (int kt = 0; kt < 8; ++kt) {
    if (kt < 7) {
#pragma unroll
      for (int nj = 0; nj < 4; ++nj)
        bfb[(kt + 1) & 1][nj] = *(const f16x8*)(bptr[nj] + (kt + 1) * 32);
    }
    // A fragments: logical chunk kt*4+lhi, physical = swizzled
    const int lc = kt * 4 + lhi;
    const int pc = (lc & 24) | ((lc & 7) ^ (lrow & 7));
    f16x8 af[8];
#pragma unroll
    for (int mi = 0; mi < 8; ++mi)
      af[mi] = *(const f16x8*)(sA + (size_t)(mi * 16 + lrow) * 256 + pc * 8);
#pragma unroll
    for (int mi = 0; mi < 8; ++mi)
#pragma unroll
      for (int nj = 0; nj < 4; ++nj)
        acc[mi][nj] = __builtin_amdgcn_mfma_f32_16x16x32_f16(af[mi], bfb[kt & 1][nj],
                                                             acc[mi][nj], 0, 0, 0);
  }

  // ---- epilogue: dist + per-row partials (registers + global, L2-hot) ----
  float yv[4];
#pragma unroll
  for (int nj = 0; nj < 4; ++nj) yv[nj] = y2[colbase + nj * 16 + lrow];

#pragma unroll
  for (int mi = 0; mi < 8; ++mi) {
    float4 x2v = *(const float4*)&x2[by * 128 + mi * 16 + lhi * 4];
    float xr[4] = {x2v.x, x2v.y, x2v.z, x2v.w};
    float rv[4];
#pragma unroll
    for (int rr = 0; rr < 4; ++rr) {
      float ssum = 0.f;
#pragma unroll
      for (int nj = 0; nj < 4; ++nj) {
        float d2 = xr[rr] + yv[nj] - 2.0f * acc[mi][nj][rr];
        d2 = fmaxf(d2, 0.0f);
        ssum += __builtin_amdgcn_sqrtf(d2 + EPSF);
      }
      ssum += __shfl_xor(ssum, 1, 64);
      ssum += __shfl_xor(ssum, 2, 64);
      ssum += __shfl_xor(ssum, 4, 64);
      ssum += __shfl_xor(ssum, 8, 64);
      rv[rr] = ssum;
    }
    if (lrow == 0)
      *(float4*)&rowacc[w][mi * 16 + lhi * 4] = make_float4(rv[0], rv[1], rv[2], rv[3]);
  }

  __syncthreads();
  if (t < 128) {
    float s = 0.f;
#pragma unroll
    for (int ww = 0; ww < 8; ++ww) s += rowacc[ww][t];
    partial[(size_t)bx * N_IDE + by * 128 + t] = s;
  }
}

// ---- Kernel 3: d[k] = sum over 32 bx-slices ----
__global__ __launch_bounds__(256) void k_dsum(const float* __restrict__ partial,
                                              float* __restrict__ d) {
  int k = blockIdx.x * 256 + threadIdx.x;
  float s = 0.f;
#pragma unroll
  for (int b = 0; b < 32; ++b) s += partial[(size_t)b * N_IDE + k];
  d[k] = s;
}

// ---- Kernel 4: loss = sum_{i,j} sqrt(((d_i-d_j)*INV_M)^2 + eps) ----
__global__ __launch_bounds__(256) void k_loss(const float* __restrict__ d,
                                              float* __restrict__ out) {
  __shared__ float sd[N_IDE];
  __shared__ float wsum[4];
  int t = threadIdx.x;
  for (int k = t; k < N_IDE; k += 256) sd[k] = d[k];
  __syncthreads();
  int tid = blockIdx.x * 256 + t;   // 65536 threads: 16 per i
  int i   = tid >> 4;
  int jl  = tid & 15;
  float di = sd[i];
  float s  = 0.f;
  for (int k = 0; k < 256; ++k) {
    float diff = (di - sd[jl + k * 16]) * INV_M;
    s += __builtin_amdgcn_sqrtf(diff * diff + EPSF);
  }
#pragma unroll
  for (int m = 1; m <= 32; m <<= 1) s += __shfl_xor(s, m, 64);
  if ((t & 63) == 0) wsum[t >> 6] = s;
  __syncthreads();
  if (t == 0) atomicAdd(out, wsum[0] + wsum[1] + wsum[2] + wsum[3]);
}

extern "C" void kernel_launch(void* const* d_in, const int* in_sizes, int n_in,
                              void* d_out, int out_size, void* d_ws, size_t ws_size,
                              hipStream_t stream) {
  (void)in_sizes; (void)n_in; (void)out_size; (void)ws_size;
  const float* ide = (const float*)d_in[0];
  const float* u   = (const float*)d_in[1];
  float* out = (float*)d_out;

  char* ws = (char*)d_ws;
  size_t off = 0;
  unsigned short* Ah = (unsigned short*)(ws + off); off += (size_t)N_IDE * D_DIM * 2;  // 2 MB
  unsigned short* Bh = (unsigned short*)(ws + off); off += (size_t)M_U  * D_DIM * 2;   // 8 MB
  float* x2      = (float*)(ws + off); off += (size_t)N_IDE * 4;
  float* y2      = (float*)(ws + off); off += (size_t)M_U * 4;
  float* partial = (float*)(ws + off); off += (size_t)32 * N_IDE * 4;                  // 512 KB
  float* dvec    = (float*)(ws + off); off += (size_t)N_IDE * 4;

  hipMemsetAsync(d_out, 0, sizeof(float), stream);
  k_conv<<<(N_IDE + M_U) / 4, 256, 0, stream>>>(ide, u, Ah, Bh, x2, y2);
  k_gemm<<<dim3(32, 32), 512, 0, stream>>>(Ah, Bh, x2, y2, partial);
  k_dsum<<<N_IDE / 256, 256, 0, stream>>>(partial, dvec);
  k_loss<<<256, 256, 0, stream>>>(dvec, out);
}